// Round 5
// baseline (356.609 us; speedup 1.0000x reference)
//
#include <hip/hip_runtime.h>

// LTLIF(tau=2, decay_input=False, hard reset) -> Linear -> BN, x2 blocks, +skip.
// T=128, B=256, C=512. GEMMs: M=T*B=32768, K=N=512.
//
// Round 5: exact i8-limb GEMM (4 limbs, scale 2^32, i32 accum exact, f64
// combine) restructured as ONE WAVE PER BLOCK, ALL-REGISTER, ZERO LDS, ZERO
// BARRIERS. Round-4 diagnosis: per-K-step __syncthreads drained the prefetch
// vmcnt to 0 -> ~900cy HBM latency on the critical path 8x/block (MfmaUtil
// 15%). Here: A panel (32 rows x 512 K = 16 KB) lives in 64 VGPRs, loaded
// once, fully coalesced (lanes {r,16+r,32+r,48+r} cover one 64B line). B
// fragments stream from L2 (W limbs = 1 MB, L2-resident) per K-step. Pure
// register dataflow -> compiler software-pipelines loads under MFMAs with
// fine-grained vmcnt (no barrier to defeat it). XCD-aware remap: each XCD
// owns a contiguous bm range (2 MB S panel per XCD L2, HBM-read once).
// BN partials fused in the wave epilogue (shfl reduce, fixed order).

typedef int i32x4 __attribute__((ext_vector_type(4)));

#define T_STEPS 128
#define BATCH   256
#define CH      512
#define BC      (BATCH * CH)        // 131072
#define MROWS   (T_STEPS * BATCH)   // 32768

// ---------------- W f32 -> 4 signed i8 limb planes (fixed point, scale 2^32) -
__global__ __launch_bounds__(256) void k_convw(const float* __restrict__ W,
                                               signed char* __restrict__ WL) {
  int i = blockIdx.x * 256 + threadIdx.x;   // 262144
  double z = (double)W[i] * 4294967296.0;
  z = fmin(fmax(z, -2147483647.0), 2147483647.0);  // safety clamp (never hit)
  int q = (int)llrint(z);
  int r = q;
  signed char l0 = (signed char)r; r = (r - l0) >> 8;
  signed char l1 = (signed char)r; r = (r - l1) >> 8;
  signed char l2 = (signed char)r; r = (r - l2) >> 8;
  signed char l3 = (signed char)r;
  WL[i]          = l0;
  WL[i + 262144] = l1;
  WL[i + 524288] = l2;
  WL[i + 786432] = l3;
}

// ---------------- LIF scan, block 1: x -> spikes (f32, bit-exact) -----------
__global__ __launch_bounds__(256) void k_lif1(const float* __restrict__ X,
                                              const float* __restrict__ wp,
                                              signed char* __restrict__ S) {
  int i4 = blockIdx.x * 256 + threadIdx.x;     // group of 4 channels
  float inv_tau = 1.0f / (1.0f + expf(-wp[0]));
  float om = 1.0f - inv_tau;
  float v0 = 0.f, v1 = 0.f, v2 = 0.f, v3 = 0.f;
  for (int t = 0; t < T_STEPS; ++t) {
    float4 x = ((const float4*)X)[(size_t)t * (BC / 4) + i4];
    char4 s;
    v0 = v0 * om + x.x; s.x = (v0 >= 1.f); v0 = s.x ? 0.f : v0;
    v1 = v1 * om + x.y; s.y = (v1 >= 1.f); v1 = s.y ? 0.f : v1;
    v2 = v2 * om + x.z; s.z = (v2 >= 1.f); v2 = s.z ? 0.f : v2;
    v3 = v3 * om + x.w; s.w = (v3 >= 1.f); v3 = s.w ? 0.f : v3;
    ((char4*)S)[(size_t)t * (BC / 4) + i4] = s;
  }
}

// ---------------- LIF scan, block 2: h = f32(f64(y)*a+b) -> spikes ----------
__global__ __launch_bounds__(256) void k_lif2(const float* __restrict__ Y,
                                              const double* __restrict__ sA,
                                              const double* __restrict__ sB,
                                              const float* __restrict__ wp,
                                              signed char* __restrict__ S) {
  int i4 = blockIdx.x * 256 + threadIdx.x;
  int c0 = (i4 * 4) & (CH - 1);
  double a0 = sA[c0], a1 = sA[c0 + 1], a2 = sA[c0 + 2], a3 = sA[c0 + 3];
  double b0 = sB[c0], b1 = sB[c0 + 1], b2 = sB[c0 + 2], b3 = sB[c0 + 3];
  float inv_tau = 1.0f / (1.0f + expf(-wp[0]));
  float om = 1.0f - inv_tau;
  float v0 = 0.f, v1 = 0.f, v2 = 0.f, v3 = 0.f;
  for (int t = 0; t < T_STEPS; ++t) {
    float4 y = ((const float4*)Y)[(size_t)t * (BC / 4) + i4];
    char4 s;
    float h0 = (float)((double)y.x * a0 + b0);
    float h1 = (float)((double)y.y * a1 + b1);
    float h2 = (float)((double)y.z * a2 + b2);
    float h3 = (float)((double)y.w * a3 + b3);
    v0 = v0 * om + h0; s.x = (v0 >= 1.f); v0 = s.x ? 0.f : v0;
    v1 = v1 * om + h1; s.y = (v1 >= 1.f); v1 = s.y ? 0.f : v1;
    v2 = v2 * om + h2; s.z = (v2 >= 1.f); v2 = s.z ? 0.f : v2;
    v3 = v3 * om + h3; s.w = (v3 >= 1.f); v3 = s.w ? 0.f : v3;
    ((char4*)S)[(size_t)t * (BC / 4) + i4] = s;
  }
}

// ---------------- i8 limb GEMM, 1 wave/block, all-register, no LDS ----------
// Wave tile 32(M) x 64(N), full K=512 in 8 steps. Fragment mapping (verified
// by the round-4 pass): A/B lane holds 16 i8 of row (lane&15)+16*frag at
// k-granule (lane>>4); C/D col=lane&15, row=(lane>>4)*4+q.
__global__ __launch_bounds__(64, 2) void k_gemm(const signed char* __restrict__ S,
                                                const signed char* __restrict__ WL,
                                                float* __restrict__ Y,
                                                double* __restrict__ sumP,
                                                double* __restrict__ sqP) {
  const int lane = threadIdx.x;
  // XCD-exclusive bm ranges: xcd = bid&7 (round-robin dispatch heuristic);
  // XCD x covers bm in [x*128, x*128+128), 8 bn-siblings of a bm adjacent.
  const int d   = blockIdx.x;            // 0..8191
  const int xcd = d & 7;
  const int s5  = d >> 3;                // 0..1023
  const int bm  = xcd * 128 + (s5 >> 3); // 0..1023 (M/32)
  const int bn  = s5 & 7;                // 0..7    (N/64)
  const int m0 = bm * 32, n0 = bn * 64;
  const int lr = lane & 15, lg = lane >> 4;

  // ---- A panel -> 64 VGPRs (16 coalesced dwordx4 loads) ----
  const signed char* aB = S + (size_t)(m0 + lr) * 512 + lg * 16;
  i32x4 a[2][8];
  #pragma unroll
  for (int m = 0; m < 2; ++m)
    #pragma unroll
    for (int kt = 0; kt < 8; ++kt)
      a[m][kt] = *(const i32x4*)(aB + m * (16 * 512) + kt * 64);

  // ---- main loop: B streamed from L2, MFMA into 128 acc VGPRs ----
  const signed char* bB = WL + (size_t)(n0 + lr) * 512 + lg * 16;
  i32x4 acc[2][4][4] = {};   // [m][n][limb]
  #pragma unroll
  for (int kt = 0; kt < 8; ++kt)
    #pragma unroll
    for (int j = 0; j < 4; ++j) {
      i32x4 b[4];
      #pragma unroll
      for (int n = 0; n < 4; ++n)
        b[n] = *(const i32x4*)(bB + j * 262144 + n * (16 * 512) + kt * 64);
      #pragma unroll
      for (int m = 0; m < 2; ++m)
        #pragma unroll
        for (int n = 0; n < 4; ++n)
          acc[m][n][j] = __builtin_amdgcn_mfma_i32_16x16x64_i8(
              a[m][kt], b[n], acc[m][n][j], 0, 0, 0);
    }

  // ---- epilogue: exact limb combine, Y write, fused BN partials ----
  const int r0 = m0 + lg * 4;
  double sc[4] = {0, 0, 0, 0}, qc[4] = {0, 0, 0, 0};
  #pragma unroll
  for (int m = 0; m < 2; ++m)
    #pragma unroll
    for (int n = 0; n < 4; ++n)
      #pragma unroll
      for (int q = 0; q < 4; ++q) {
        double yv = (((double)acc[m][n][3][q] * 256.0 + (double)acc[m][n][2][q]) * 256.0
                     + (double)acc[m][n][1][q]) * 256.0 + (double)acc[m][n][0][q];
        float yf = (float)(yv * 0x1p-32);
        Y[(size_t)(r0 + m * 16 + q) * 512 + n0 + n * 16 + lr] = yf;
        double yd = (double)yf;
        sc[n] += yd; qc[n] += yd * yd;
      }
  #pragma unroll
  for (int n = 0; n < 4; ++n) {          // reduce lanes {l, l^16, l^32, l^48}
    sc[n] += __shfl_xor(sc[n], 16); sc[n] += __shfl_xor(sc[n], 32);
    qc[n] += __shfl_xor(qc[n], 16); qc[n] += __shfl_xor(qc[n], 32);
  }
  if (lane < 16) {
    #pragma unroll
    for (int n = 0; n < 4; ++n) {
      int ch = n0 + n * 16 + lane;
      sumP[(size_t)ch * 1024 + bm] = sc[n];
      sqP [(size_t)ch * 1024 + bm] = qc[n];
    }
  }
}

// ---------------- BN stats stage 2: per-channel a, b (tree, deterministic) --
__global__ __launch_bounds__(256) void k_stats2(const double* __restrict__ sumP,
                                                const double* __restrict__ sqP,
                                                const float* __restrict__ gamma,
                                                const float* __restrict__ beta,
                                                double* __restrict__ sA,
                                                double* __restrict__ sB) {
  __shared__ double shS[256], shQ[256];
  int c = blockIdx.x;       // 512 blocks, one channel each
  int t = threadIdx.x;
  const double* ps = sumP + (size_t)c * 1024;
  const double* pq = sqP  + (size_t)c * 1024;
  double s = 0, q = 0;
  #pragma unroll
  for (int u = 0; u < 4; ++u) { s += ps[t * 4 + u]; q += pq[t * 4 + u]; }
  shS[t] = s; shQ[t] = q;
  __syncthreads();
  for (int w = 128; w >= 1; w >>= 1) {
    if (t < w) { shS[t] += shS[t + w]; shQ[t] += shQ[t + w]; }
    __syncthreads();
  }
  if (t == 0) {
    const double invN = 1.0 / 32768.0;
    double mean = shS[0] * invN;
    double var  = shQ[0] * invN - mean * mean;
    double rstd = rsqrt(var + 1e-5);
    double a = (double)gamma[c] * rstd;
    sA[c] = a;
    sB[c] = (double)beta[c] - mean * a;
  }
}

// ---------------- final: out = f32(f64(y)*a + b + x) ------------------------
__global__ __launch_bounds__(256) void k_final(float* __restrict__ Y,
                                               const float* __restrict__ X,
                                               const double* __restrict__ sA,
                                               const double* __restrict__ sB) {
  size_t i = (size_t)blockIdx.x * 256 + threadIdx.x;  // float4 index
  int c0 = (int)((i * 4) & (CH - 1));
  float4 y = ((const float4*)Y)[i];
  float4 x = ((const float4*)X)[i];
  float4 o;
  o.x = (float)((double)y.x * sA[c0 + 0] + sB[c0 + 0] + (double)x.x);
  o.y = (float)((double)y.y * sA[c0 + 1] + sB[c0 + 1] + (double)x.y);
  o.z = (float)((double)y.z * sA[c0 + 2] + sB[c0 + 2] + (double)x.z);
  o.w = (float)((double)y.w * sA[c0 + 3] + sB[c0 + 3] + (double)x.w);
  ((float4*)Y)[i] = o;
}

// ---------------- launch ----------------------------------------------------
extern "C" void kernel_launch(void* const* d_in, const int* in_sizes, int n_in,
                              void* d_out, int out_size, void* d_ws, size_t ws_size,
                              hipStream_t stream) {
  (void)in_sizes; (void)n_in; (void)out_size; (void)ws_size;

  const float* x   = (const float*)d_in[0];
  const float* w0  = (const float*)d_in[1];
  const float* W0  = (const float*)d_in[2];
  // d_in[3] = b0: absorbed by BN
  const float* g0  = (const float*)d_in[4];
  const float* be0 = (const float*)d_in[5];
  const float* w1  = (const float*)d_in[6];
  const float* W1  = (const float*)d_in[7];
  // d_in[8] = b1: absorbed by BN
  const float* g1  = (const float*)d_in[9];
  const float* be1 = (const float*)d_in[10];
  float* Y = (float*)d_out;   // y1, then y2, then final output

  char* ws = (char*)d_ws;
  signed char* WL0  = (signed char*)(ws + 0x0000000);  // 1 MB (4 planes)
  signed char* WL1  = (signed char*)(ws + 0x0100000);  // 1 MB
  signed char* spk  = (signed char*)(ws + 0x0200000);  // 16.78 MB
  double*      sumP = (double*)(ws + 0x1200000);       // 4 MB [512][1024]
  double*      sqP  = (double*)(ws + 0x1600000);       // 4 MB
  double*      sA   = (double*)(ws + 0x1A00000);       // 4 KB
  double*      sB   = (double*)(ws + 0x1A02000);       // 4 KB

  k_convw<<<1024, 256, 0, stream>>>(W0, WL0);
  k_convw<<<1024, 256, 0, stream>>>(W1, WL1);

  // block 1
  k_lif1 <<<BC / 4 / 256, 256, 0, stream>>>(x, w0, spk);
  k_gemm <<<(MROWS / 32) * (CH / 64), 64, 0, stream>>>(spk, WL0, Y, sumP, sqP);
  k_stats2<<<512, 256, 0, stream>>>(sumP, sqP, g0, be0, sA, sB);

  // block 2 (BN affine of block 1 fused into LIF input, f64->f32 once)
  k_lif2 <<<BC / 4 / 256, 256, 0, stream>>>(Y, sA, sB, w1, spk);
  k_gemm <<<(MROWS / 32) * (CH / 64), 64, 0, stream>>>(spk, WL1, Y, sumP, sqP);
  k_stats2<<<512, 256, 0, stream>>>(sumP, sqP, g1, be1, sA, sB);

  // out = BN(y2) + x
  k_final<<<(MROWS * CH) / (4 * 256), 256, 0, stream>>>(Y, x, sA, sB);
}

// Round 6
// 210.248 us; speedup vs baseline: 1.6961x; 1.6961x over previous
//
#include <hip/hip_runtime.h>

// LTLIF(tau=2, decay_input=False, hard reset) -> Linear -> BN, x2 blocks, +skip.
// T=128, B=256, C=512. GEMMs: M=T*B=32768, K=N=512.
//
// Round 6: round-4 i8-limb GEMM (exact: 4 limbs @2^32, i32 accum, f64 combine)
// with the barrier discipline fixed. Round-4 used __syncthreads per K-step,
// which drains vmcnt(0) -> the just-issued prefetch stalled the pipe (MfmaUtil
// 15%). Round-5 (barrier-free all-register streaming) refuted "the compiler
// will pipeline it": 9% MfmaUtil, latency-serialized loads. Here: T4 counted
// vmcnt + raw s_barrier. Per K-step: STAGE(next) [6 loads] stays IN FLIGHT
// through the step; s_waitcnt vmcnt(6) waits only the PREVIOUS stage, then
// s_barrier publishes it; ds_read+MFMA; s_waitcnt lgkmcnt(0) + s_barrier
// releases the buffer for overwrite. Also: XCD-partitioned bid map (each XCD
// owns 32 bm panels = 2 MB S slice, L2-resident across its 8 bn) -> S read
// from HBM once total.

typedef int i32x4 __attribute__((ext_vector_type(4)));

#define T_STEPS 128
#define BATCH   256
#define CH      512
#define BC      (BATCH * CH)        // 131072
#define MROWS   (T_STEPS * BATCH)   // 32768

// ---------------- async global->LDS (16B per lane, wave-uniform LDS base) ----
__device__ __forceinline__ void llds16(const void* g, void* l) {
  __builtin_amdgcn_global_load_lds(
      (const __attribute__((address_space(1))) void*)g,
      (__attribute__((address_space(3))) void*)l, 16, 0, 0);
}

// ---------------- W f32 -> 4 signed i8 limb planes (fixed point, scale 2^32) -
__global__ __launch_bounds__(256) void k_convw(const float* __restrict__ W,
                                               signed char* __restrict__ WL) {
  int i = blockIdx.x * 256 + threadIdx.x;   // 262144
  double z = (double)W[i] * 4294967296.0;
  z = fmin(fmax(z, -2147483647.0), 2147483647.0);  // safety clamp (never hit)
  int q = (int)llrint(z);
  int r = q;
  signed char l0 = (signed char)r; r = (r - l0) >> 8;
  signed char l1 = (signed char)r; r = (r - l1) >> 8;
  signed char l2 = (signed char)r; r = (r - l2) >> 8;
  signed char l3 = (signed char)r;
  WL[i]          = l0;
  WL[i + 262144] = l1;
  WL[i + 524288] = l2;
  WL[i + 786432] = l3;
}

// ---------------- LIF scan, block 1: x -> spikes (f32, bit-exact) -----------
__global__ __launch_bounds__(256) void k_lif1(const float* __restrict__ X,
                                              const float* __restrict__ wp,
                                              signed char* __restrict__ S) {
  int i4 = blockIdx.x * 256 + threadIdx.x;     // group of 4 channels
  float inv_tau = 1.0f / (1.0f + expf(-wp[0]));
  float om = 1.0f - inv_tau;
  float v0 = 0.f, v1 = 0.f, v2 = 0.f, v3 = 0.f;
  for (int t = 0; t < T_STEPS; ++t) {
    float4 x = ((const float4*)X)[(size_t)t * (BC / 4) + i4];
    char4 s;
    v0 = v0 * om + x.x; s.x = (v0 >= 1.f); v0 = s.x ? 0.f : v0;
    v1 = v1 * om + x.y; s.y = (v1 >= 1.f); v1 = s.y ? 0.f : v1;
    v2 = v2 * om + x.z; s.z = (v2 >= 1.f); v2 = s.z ? 0.f : v2;
    v3 = v3 * om + x.w; s.w = (v3 >= 1.f); v3 = s.w ? 0.f : v3;
    ((char4*)S)[(size_t)t * (BC / 4) + i4] = s;
  }
}

// ---------------- LIF scan, block 2: h = f32(f64(y)*a+b) -> spikes ----------
__global__ __launch_bounds__(256) void k_lif2(const float* __restrict__ Y,
                                              const double* __restrict__ sA,
                                              const double* __restrict__ sB,
                                              const float* __restrict__ wp,
                                              signed char* __restrict__ S) {
  int i4 = blockIdx.x * 256 + threadIdx.x;
  int c0 = (i4 * 4) & (CH - 1);
  double a0 = sA[c0], a1 = sA[c0 + 1], a2 = sA[c0 + 2], a3 = sA[c0 + 3];
  double b0 = sB[c0], b1 = sB[c0 + 1], b2 = sB[c0 + 2], b3 = sB[c0 + 3];
  float inv_tau = 1.0f / (1.0f + expf(-wp[0]));
  float om = 1.0f - inv_tau;
  float v0 = 0.f, v1 = 0.f, v2 = 0.f, v3 = 0.f;
  for (int t = 0; t < T_STEPS; ++t) {
    float4 y = ((const float4*)Y)[(size_t)t * (BC / 4) + i4];
    char4 s;
    float h0 = (float)((double)y.x * a0 + b0);
    float h1 = (float)((double)y.y * a1 + b1);
    float h2 = (float)((double)y.z * a2 + b2);
    float h3 = (float)((double)y.w * a3 + b3);
    v0 = v0 * om + h0; s.x = (v0 >= 1.f); v0 = s.x ? 0.f : v0;
    v1 = v1 * om + h1; s.y = (v1 >= 1.f); v1 = s.y ? 0.f : v1;
    v2 = v2 * om + h2; s.z = (v2 >= 1.f); v2 = s.z ? 0.f : v2;
    v3 = v3 * om + h3; s.w = (v3 >= 1.f); v3 = s.w ? 0.f : v3;
    ((char4*)S)[(size_t)t * (BC / 4) + i4] = s;
  }
}

// ---------------- i8 limb GEMM + fused BN partial stats ----------------------
// Tile 128(M) x 64(N), BK=64, dbuf LDS, 4 waves (2Mx2N); wave tile 64x32.
// Counted-vmcnt pipeline: STAGE(next) in flight across the whole K-step.
// 16B XOR swizzle on both sides (round-4 verified, conflicts = 0).
__global__ __launch_bounds__(256) void k_gemm(const signed char* __restrict__ S,
                                              const signed char* __restrict__ WL,
                                              float* __restrict__ Y,
                                              double* __restrict__ sumP,
                                              double* __restrict__ sqP) {
  __shared__ __align__(16) signed char Ab[2][128 * 64];      // 8 KB x2
  __shared__ __align__(16) signed char Bb[2][4][64 * 64];    // 16 KB x2

  const int tid  = threadIdx.x;
  const int wid  = tid >> 6;
  const int lane = tid & 63;
  // XCD partition: xcd = bid&7 (round-robin dispatch). Each XCD owns bm in
  // [xcd*32, xcd*32+32) -> 2 MB S slice resident in its L2, reused over bn.
  const int bid   = blockIdx.x;
  const int xcd   = bid & 7;
  const int local = bid >> 3;             // 0..255
  const int bn    = local & 7;            // 0..7   (N/64)
  const int bm    = xcd * 32 + (local >> 3);   // 0..255 (M/128)
  const int m0 = bm * 128, n0 = bn * 64;
  const int wm = wid >> 1, wn = wid & 1;

  i32x4 acc[4][2][4] = {};   // [m-frag][n-frag][limb]

  // stage one BK=64 tile into buffer `buf` (pre-swizzled source granules)
  auto STAGE = [&](int buf, int kt) {
    #pragma unroll
    for (int p = 0; p < 2; ++p) {                 // A: 128 rows x 4 granules
      int cid = p * 256 + tid, row = cid >> 2, gl = cid & 3;
      int gg = gl ^ ((row >> 1) & 3);
      llds16(S + (size_t)(m0 + row) * 512 + kt + gg * 16,
             (char*)Ab[buf] + p * 4096 + wid * 1024);
    }
    #pragma unroll
    for (int j = 0; j < 4; ++j) {                 // B: 4 limbs x 64 rows x 4
      int row = tid >> 2, gl = tid & 3;
      int gg = gl ^ ((row >> 1) & 3);
      llds16(WL + (size_t)j * 262144 + (size_t)(n0 + row) * 512 + kt + gg * 16,
             (char*)Bb[buf][j] + wid * 1024);
    }
  };

  STAGE(0, 0);                 // 6 loads in flight
  #pragma unroll
  for (int i = 0; i < 8; ++i) {
    const int cur = i & 1;
    if (i < 7) STAGE(cur ^ 1, (i + 1) * 64);      // +6 loads (12 outstanding)

    // Wait only the PREVIOUS stage (leave this iter's 6 in flight), then
    // publish cross-wave. Memory clobbers stop the compiler moving LDS ops.
    if (i < 7) asm volatile("s_waitcnt vmcnt(6)" ::: "memory");
    else       asm volatile("s_waitcnt vmcnt(0)" ::: "memory");
    __builtin_amdgcn_s_barrier();
    asm volatile("" ::: "memory");

    i32x4 a[4];
    #pragma unroll
    for (int m = 0; m < 4; ++m) {
      int r = wm * 64 + m * 16 + (lane & 15);
      int g = (lane >> 4) ^ ((r >> 1) & 3);
      a[m] = *(const i32x4*)(Ab[cur] + r * 64 + g * 16);
    }
    #pragma unroll
    for (int j = 0; j < 4; ++j) {
      i32x4 b[2];
      #pragma unroll
      for (int n = 0; n < 2; ++n) {
        int r = wn * 32 + n * 16 + (lane & 15);
        int g = (lane >> 4) ^ ((r >> 1) & 3);
        b[n] = *(const i32x4*)(Bb[cur][j] + r * 64 + g * 16);
      }
      #pragma unroll
      for (int m = 0; m < 4; ++m)
        #pragma unroll
        for (int n = 0; n < 2; ++n)
          acc[m][n][j] = __builtin_amdgcn_mfma_i32_16x16x64_i8(
              a[m], b[n], acc[m][n][j], 0, 0, 0);
    }

    // All of this wave's ds_reads retired -> buffer may be overwritten next
    // iter. MFMAs keep draining past the barrier (reg-only) = the overlap.
    asm volatile("s_waitcnt lgkmcnt(0)" ::: "memory");
    __builtin_amdgcn_s_barrier();
  }

  // ---- epilogue: exact limb combine, Y write, fused BN partials -------------
  // C/D: col = lane&15 (+16n +32wn), row = (lane>>4)*4 + q (+16m +64wm)
  const int r0 = m0 + wm * 64 + (lane >> 4) * 4;
  const int cl = wn * 32 + (lane & 15);      // block-local col of n=0 frag
  double s0 = 0, q0 = 0, s1 = 0, q1 = 0;
  #pragma unroll
  for (int m = 0; m < 4; ++m)
    #pragma unroll
    for (int n = 0; n < 2; ++n)
      #pragma unroll
      for (int q = 0; q < 4; ++q) {
        double yv = (((double)acc[m][n][3][q] * 256.0 + (double)acc[m][n][2][q]) * 256.0
                     + (double)acc[m][n][1][q]) * 256.0 + (double)acc[m][n][0][q];
        float yf = (float)(yv * 0x1p-32);
        Y[(size_t)(r0 + m * 16 + q) * 512 + n0 + cl + n * 16] = yf;
        double yd = (double)yf;
        if (n == 0) { s0 += yd; q0 += yd * yd; }
        else        { s1 += yd; q1 += yd * yd; }
      }
  s0 += __shfl_xor(s0, 16); s0 += __shfl_xor(s0, 32);
  q0 += __shfl_xor(q0, 16); q0 += __shfl_xor(q0, 32);
  s1 += __shfl_xor(s1, 16); s1 += __shfl_xor(s1, 32);
  q1 += __shfl_xor(q1, 16); q1 += __shfl_xor(q1, 32);

  double* shS = (double*)Ab[0];        // reuse LDS (dead, post-barrier)
  double* shQ = shS + 128;
  if (lane < 16) {
    shS[wm * 64 + cl]      = s0;  shQ[wm * 64 + cl]      = q0;
    shS[wm * 64 + cl + 16] = s1;  shQ[wm * 64 + cl + 16] = q1;
  }
  __syncthreads();
  if (tid < 64) {   // cross-wave (wm) add; local channel = tid; fixed order
    sumP[(size_t)(n0 + tid) * 256 + bm] = shS[tid] + shS[64 + tid];
    sqP [(size_t)(n0 + tid) * 256 + bm] = shQ[tid] + shQ[64 + tid];
  }
}

// ---------------- BN stats stage 2: per-channel a, b (tree, deterministic) --
__global__ __launch_bounds__(256) void k_stats2(const double* __restrict__ sumP,
                                                const double* __restrict__ sqP,
                                                const float* __restrict__ gamma,
                                                const float* __restrict__ beta,
                                                double* __restrict__ sA,
                                                double* __restrict__ sB) {
  __shared__ double shS[256], shQ[256];
  int c = blockIdx.x;       // 512 blocks, one channel each
  int t = threadIdx.x;      // 256 partials, coalesced
  shS[t] = sumP[(size_t)c * 256 + t];
  shQ[t] = sqP [(size_t)c * 256 + t];
  __syncthreads();
  for (int w = 128; w >= 1; w >>= 1) {
    if (t < w) { shS[t] += shS[t + w]; shQ[t] += shQ[t + w]; }
    __syncthreads();
  }
  if (t == 0) {
    const double invN = 1.0 / 32768.0;
    double mean = shS[0] * invN;
    double var  = shQ[0] * invN - mean * mean;
    double rstd = rsqrt(var + 1e-5);
    double a = (double)gamma[c] * rstd;
    sA[c] = a;
    sB[c] = (double)beta[c] - mean * a;
  }
}

// ---------------- final: out = f32(f64(y)*a + b + x) ------------------------
__global__ __launch_bounds__(256) void k_final(float* __restrict__ Y,
                                               const float* __restrict__ X,
                                               const double* __restrict__ sA,
                                               const double* __restrict__ sB) {
  size_t i = (size_t)blockIdx.x * 256 + threadIdx.x;  // float4 index
  int c0 = (int)((i * 4) & (CH - 1));
  float4 y = ((const float4*)Y)[i];
  float4 x = ((const float4*)X)[i];
  float4 o;
  o.x = (float)((double)y.x * sA[c0 + 0] + sB[c0 + 0] + (double)x.x);
  o.y = (float)((double)y.y * sA[c0 + 1] + sB[c0 + 1] + (double)x.y);
  o.z = (float)((double)y.z * sA[c0 + 2] + sB[c0 + 2] + (double)x.z);
  o.w = (float)((double)y.w * sA[c0 + 3] + sB[c0 + 3] + (double)x.w);
  ((float4*)Y)[i] = o;
}

// ---------------- launch ----------------------------------------------------
extern "C" void kernel_launch(void* const* d_in, const int* in_sizes, int n_in,
                              void* d_out, int out_size, void* d_ws, size_t ws_size,
                              hipStream_t stream) {
  (void)in_sizes; (void)n_in; (void)out_size; (void)ws_size;

  const float* x   = (const float*)d_in[0];
  const float* w0  = (const float*)d_in[1];
  const float* W0  = (const float*)d_in[2];
  // d_in[3] = b0: absorbed by BN
  const float* g0  = (const float*)d_in[4];
  const float* be0 = (const float*)d_in[5];
  const float* w1  = (const float*)d_in[6];
  const float* W1  = (const float*)d_in[7];
  // d_in[8] = b1: absorbed by BN
  const float* g1  = (const float*)d_in[9];
  const float* be1 = (const float*)d_in[10];
  float* Y = (float*)d_out;   // y1, then y2, then final output

  char* ws = (char*)d_ws;
  signed char* WL0  = (signed char*)(ws + 0x0000000);  // 1 MB (4 planes)
  signed char* WL1  = (signed char*)(ws + 0x0100000);  // 1 MB
  signed char* spk  = (signed char*)(ws + 0x0200000);  // 16.78 MB
  double*      sumP = (double*)(ws + 0x1200000);       // 1 MB [512][256]
  double*      sqP  = (double*)(ws + 0x1300000);       // 1 MB
  double*      sA   = (double*)(ws + 0x1400000);       // 4 KB
  double*      sB   = (double*)(ws + 0x1402000);       // 4 KB

  k_convw<<<1024, 256, 0, stream>>>(W0, WL0);
  k_convw<<<1024, 256, 0, stream>>>(W1, WL1);

  // block 1
  k_lif1 <<<BC / 4 / 256, 256, 0, stream>>>(x, w0, spk);
  k_gemm <<<(MROWS / 128) * (CH / 64), 256, 0, stream>>>(spk, WL0, Y, sumP, sqP);
  k_stats2<<<512, 256, 0, stream>>>(sumP, sqP, g0, be0, sA, sB);

  // block 2 (BN affine of block 1 fused into LIF input, f64->f32 once)
  k_lif2 <<<BC / 4 / 256, 256, 0, stream>>>(Y, sA, sB, w1, spk);
  k_gemm <<<(MROWS / 128) * (CH / 64), 256, 0, stream>>>(spk, WL1, Y, sumP, sqP);
  k_stats2<<<512, 256, 0, stream>>>(sumP, sqP, g1, be1, sA, sB);

  // out = BN(y2) + x
  k_final<<<(MROWS * CH) / (4 * 256), 256, 0, stream>>>(Y, x, sA, sB);
}